// Round 7
// baseline (182.863 us; speedup 1.0000x reference)
//
#include <hip/hip_runtime.h>
#include <math.h>

// ColumnBlockAttention via bf16 MFMA: b=16, t=8192, e=64, BLOCK=64, n_cols=128
// d_out = [out: b*t*64 f32 | A: b*t*128 f32].
//
// One workgroup per (batch, group of MPG=2 m-blocks). Kc/VcT staged once
// (single barrier), then the loop runs BARRIER-FREE: Aw is wave-private
// (wave w writes AND reads only rows [16w,16w+16)), so same-wave lgkmcnt
// ordering suffices — no vmcnt(0) store drains in the loop.
//   convert prefetched Q -> GEMM1 Z=Q.Kc^T (mfma 16x16x32 bf16)
//   -> prefetch next Q -> mask/exp2/row-reduce -> normalize in regs
//   -> A stored directly from f32 accs -> Aw(bf16)->LDS (wave-private
//      transpose for GEMM2 A-frags) -> GEMM2 out=Aw.Vc -> direct stores.
// exp trick: 0.125*log2(e) folded into Q pre-scale, softmax via exp2f.
// LDS 53248 B -> 3 wgs/CU; grid 1024 -> 12 waves/CU.
// Layouts (HW-verified m89/m120): A-frag A[m=lane&15][k=(lane>>4)*8+j],
// B-frag B[k][n]: n=lane&15, k=(lane>>4)*8+j; C/D col=lane&15,
// row=(lane>>4)*4+reg.

#define TSEQ 8192
#define EDIM 64
#define NCOL 128
#define NBATCH 16
#define MPG 2            // m-blocks per workgroup

typedef __attribute__((ext_vector_type(8))) short short8;
typedef __attribute__((ext_vector_type(4))) float f32x4;

__device__ __forceinline__ unsigned short f2bf(float f) {   // RTNE bf16
    unsigned int u = __float_as_uint(f);
    return (unsigned short)((u + 0x7fffu + ((u >> 16) & 1u)) >> 16);
}

__global__ __launch_bounds__(256, 3)
void cba_kernel(const float* __restrict__ Q,
                const float* __restrict__ K,
                const float* __restrict__ V,
                float* __restrict__ Out,
                float* __restrict__ A)
{
    __shared__ unsigned short Kc[NCOL][72];    // Kc[col][dim]   (18432 B)
    __shared__ unsigned short VcT[EDIM][136];  // VcT[dim][col]  (17408 B)
    __shared__ unsigned short Aw[64][136];     // weights [row][col] (17408 B)

    const int tid  = threadIdx.x;
    const int lane = tid & 63;
    const int wid  = tid >> 6;                 // 0..3: rows [16w,16w+16)
    const int b    = blockIdx.x >> 6;          // 0..15
    const int mg   = blockIdx.x & 63;          // m-group: m = 2*mg + it

    const int c   = lane & 15;                 // col-in-tile / n index
    const int kq  = (lane >> 4) << 3;          // 8-dim k-group base
    const int rb  = (wid << 4) + ((lane >> 4) << 2);  // C-layout row base (in 64)
    const int qr  = (wid << 4) + c;            // A-frag row (in 64)

    // 0.125 * log2(e): softmax(x/8) == exp2(QSCALE * x) / sum
    const float QSCALE = 0.18033688011112042f;

    // ---- prefetch Q for iteration 0 (issues before staging loads) ----
    float4 qf[4];
    {
        const int m0 = mg * MPG;
        const float* qp = Q + ((size_t)b * TSEQ + (m0 << 6) + qr) * EDIM;
        qf[0] = *(const float4*)(qp + kq);
        qf[1] = *(const float4*)(qp + kq + 4);
        qf[2] = *(const float4*)(qp + 32 + kq);
        qf[3] = *(const float4*)(qp + 32 + kq + 4);
    }

    // ---- stage Kc (bf16) and VcT (bf16, transposed) ONCE per workgroup ----
    {
        const int j = tid >> 1;                // column 0..127
        const int h = (tid & 1) << 5;          // dim half: 0 or 32
        const size_t src = ((size_t)b * TSEQ + (j * 64 + 63)) * EDIM + h;
        const float4* ks = (const float4*)(K + src);
        const float4* vs = (const float4*)(V + src);
        #pragma unroll
        for (int t = 0; t < 8; ++t) {
            float4 kf = ks[t];
            unsigned int p0 = (unsigned int)f2bf(kf.x) | ((unsigned int)f2bf(kf.y) << 16);
            unsigned int p1 = (unsigned int)f2bf(kf.z) | ((unsigned int)f2bf(kf.w) << 16);
            *(unsigned int*)&Kc[j][h + 4 * t]     = p0;
            *(unsigned int*)&Kc[j][h + 4 * t + 2] = p1;
        }
        #pragma unroll
        for (int t = 0; t < 8; ++t) {
            float4 vf = vs[t];
            VcT[h + 4 * t + 0][j] = f2bf(vf.x);
            VcT[h + 4 * t + 1][j] = f2bf(vf.y);
            VcT[h + 4 * t + 2][j] = f2bf(vf.z);
            VcT[h + 4 * t + 3][j] = f2bf(vf.w);
        }
    }
    __syncthreads();                           // the ONLY barrier

    #pragma unroll
    for (int it = 0; it < MPG; ++it) {
        const int m = mg * MPG + it;
        const size_t rowbase = (size_t)b * TSEQ + ((size_t)m << 6);

        // ---- convert prefetched Q (pre-scaled by 0.125*log2e) ----
        short8 qa[2];
        #pragma unroll
        for (int s = 0; s < 2; ++s) {
            float4 f0 = qf[2 * s], f1 = qf[2 * s + 1];
            short8 v;
            v[0] = (short)f2bf(f0.x * QSCALE); v[1] = (short)f2bf(f0.y * QSCALE);
            v[2] = (short)f2bf(f0.z * QSCALE); v[3] = (short)f2bf(f0.w * QSCALE);
            v[4] = (short)f2bf(f1.x * QSCALE); v[5] = (short)f2bf(f1.y * QSCALE);
            v[6] = (short)f2bf(f1.z * QSCALE); v[7] = (short)f2bf(f1.w * QSCALE);
            qa[s] = v;
        }

        // ---- GEMM1: 8 col-tiles x 2 K-steps ----
        f32x4 acc[8];
        #pragma unroll
        for (int t = 0; t < 8; ++t) acc[t] = (f32x4)0.f;
        #pragma unroll
        for (int t = 0; t < 8; ++t) {
            const unsigned short* kr = &Kc[(t << 4) + c][0];
            short8 b0 = *(const short8*)(kr + kq);
            short8 b1 = *(const short8*)(kr + 32 + kq);
            acc[t] = __builtin_amdgcn_mfma_f32_16x16x32_bf16(qa[0], b0, acc[t], 0, 0, 0);
            acc[t] = __builtin_amdgcn_mfma_f32_16x16x32_bf16(qa[1], b1, acc[t], 0, 0, 0);
        }

        // ---- prefetch Q for next iteration ----
        if (it + 1 < MPG) {
            const float* qp = Q + (rowbase + 64 + qr) * EDIM;
            qf[0] = *(const float4*)(qp + kq);
            qf[1] = *(const float4*)(qp + kq + 4);
            qf[2] = *(const float4*)(qp + 32 + kq);
            qf[3] = *(const float4*)(qp + 32 + kq + 4);
        }

        // ---- mask + exp2 + row sums; normalize in registers ----
        #pragma unroll
        for (int reg = 0; reg < 4; ++reg) {
            const int r  = rb + reg;
            const int nv = m + (r == 63 ? 1 : 0);
            float sum = 0.f;
            #pragma unroll
            for (int t = 0; t < 8; ++t) {
                const int jc = (t << 4) + c;
                float e = (jc < nv) ? exp2f(acc[t][reg]) : 0.f;
                acc[t][reg] = e;
                sum += e;
            }
            sum += __shfl_xor(sum, 1); sum += __shfl_xor(sum, 2);
            sum += __shfl_xor(sum, 4); sum += __shfl_xor(sum, 8);
            const float rinv = (sum > 0.f) ? 1.0f / sum : 0.f;
            #pragma unroll
            for (int t = 0; t < 8; ++t) acc[t][reg] *= rinv;
        }

        // ---- A output: directly from f32 accumulators (C-layout) ----
        #pragma unroll
        for (int reg = 0; reg < 4; ++reg) {
            float* ap = A + (rowbase + rb + reg) * NCOL + c;
            #pragma unroll
            for (int t = 0; t < 8; ++t) ap[t << 4] = acc[t][reg];
        }

        // ---- Aw (bf16) -> LDS; wave-private rows, no barrier needed ----
        #pragma unroll
        for (int reg = 0; reg < 4; ++reg) {
            #pragma unroll
            for (int t = 0; t < 8; ++t)
                Aw[rb + reg][(t << 4) + c] = f2bf(acc[t][reg]);
        }

        // ---- GEMM2: out(64x64) = Aw(64x128) . Vc(128x64) ----
        short8 af[4];
        {
            const unsigned short* ar = &Aw[qr][0];
            #pragma unroll
            for (int s = 0; s < 4; ++s) af[s] = *(const short8*)(ar + (s << 5) + kq);
        }
        f32x4 oacc[4];
        #pragma unroll
        for (int t = 0; t < 4; ++t) oacc[t] = (f32x4)0.f;
        #pragma unroll
        for (int t = 0; t < 4; ++t) {
            const unsigned short* vr = &VcT[(t << 4) + c][0];
            #pragma unroll
            for (int s = 0; s < 4; ++s) {
                short8 vb = *(const short8*)(vr + (s << 5) + kq);
                oacc[t] = __builtin_amdgcn_mfma_f32_16x16x32_bf16(af[s], vb, oacc[t], 0, 0, 0);
            }
        }

        // ---- Out: directly from C-layout regs ----
        #pragma unroll
        for (int t = 0; t < 4; ++t) {
            #pragma unroll
            for (int reg = 0; reg < 4; ++reg)
                Out[(rowbase + rb + reg) * EDIM + (t << 4) + c] = oacc[t][reg];
        }
    }
}

extern "C" void kernel_launch(void* const* d_in, const int* in_sizes, int n_in,
                              void* d_out, int out_size, void* d_ws, size_t ws_size,
                              hipStream_t stream) {
    const float* Q = (const float*)d_in[0];
    const float* K = (const float*)d_in[1];
    const float* V = (const float*)d_in[2];
    float* Out = (float*)d_out;
    float* A   = Out + (size_t)NBATCH * TSEQ * EDIM;

    // 1024 workgroups x 256 threads: one per (batch, 2 m-blocks); 3 wgs/CU res.
    cba_kernel<<<dim3(NBATCH * 64), dim3(256), 0, stream>>>(Q, K, V, Out, A);
}

// Round 8
// 174.431 us; speedup vs baseline: 1.0483x; 1.0483x over previous
//
#include <hip/hip_runtime.h>
#include <math.h>

// ColumnBlockAttention via bf16 MFMA: b=16, t=8192, e=64, BLOCK=64, n_cols=128
// d_out = [out: b*t*64 f32 | A: b*t*128 f32].
//
// One workgroup per (batch, group of MPG=4 m-blocks); grid 512 = 256 CUs x 2,
// __launch_bounds__(256,2) -> every CU holds exactly 2 wgs, no partial tail.
// Kc/VcT staged once (single barrier), then the 4-iteration loop runs
// BARRIER-FREE: Aw is wave-private (wave w writes AND reads only rows
// [16w,16w+16)), so same-wave LDS ordering suffices — no vmcnt(0) store
// drains inside the loop; iterations of different waves pipeline each other.
//   convert prefetched Q -> GEMM1 Z=Q.Kc^T (mfma 16x16x32 bf16)
//   -> prefetch next Q -> mask/exp2/row-reduce -> normalize in regs
//   -> Aw(bf16)->LDS (wave-private transpose) -> A stored from f32 accs
//   -> GEMM2 out=Aw.Vc -> Out stored directly from C-layout regs.
// exp trick: 0.125*log2(e) folded into Q pre-scale, softmax via exp2f.
// Layouts (HW-verified m89/m120): A-frag A[m=lane&15][k=(lane>>4)*8+j],
// B-frag B[k][n]: n=lane&15, k=(lane>>4)*8+j; C/D col=lane&15,
// row=(lane>>4)*4+reg.

#define TSEQ 8192
#define EDIM 64
#define NCOL 128
#define NBATCH 16
#define MPG 4            // m-blocks per workgroup

typedef __attribute__((ext_vector_type(8))) short short8;
typedef __attribute__((ext_vector_type(4))) float f32x4;

__device__ __forceinline__ unsigned short f2bf(float f) {   // RTNE bf16
    unsigned int u = __float_as_uint(f);
    return (unsigned short)((u + 0x7fffu + ((u >> 16) & 1u)) >> 16);
}

__global__ __launch_bounds__(256, 2)
void cba_kernel(const float* __restrict__ Q,
                const float* __restrict__ K,
                const float* __restrict__ V,
                float* __restrict__ Out,
                float* __restrict__ A)
{
    __shared__ unsigned short Kc[NCOL][72];    // Kc[col][dim]   (18432 B)
    __shared__ unsigned short VcT[EDIM][136];  // VcT[dim][col]  (17408 B)
    __shared__ unsigned short Aw[64][136];     // weights [row][col] (17408 B)

    const int tid  = threadIdx.x;
    const int lane = tid & 63;
    const int wid  = tid >> 6;                 // 0..3: rows [16w,16w+16)
    const int b    = blockIdx.x >> 5;          // 0..15
    const int mg   = blockIdx.x & 31;          // m-group: m = 4*mg + it

    const int c   = lane & 15;                 // col-in-tile / n index
    const int kq  = (lane >> 4) << 3;          // 8-dim k-group base
    const int rb  = (wid << 4) + ((lane >> 4) << 2);  // C-layout row base (in 64)
    const int qr  = (wid << 4) + c;            // A-frag row (in 64)

    // 0.125 * log2(e): softmax(x/8) == exp2(QSCALE * x) / sum
    const float QSCALE = 0.18033688011112042f;

    // ---- prefetch Q for iteration 0 (issues before staging loads) ----
    float4 qf[4];
    {
        const int m0 = mg * MPG;
        const float* qp = Q + ((size_t)b * TSEQ + (m0 << 6) + qr) * EDIM;
        qf[0] = *(const float4*)(qp + kq);
        qf[1] = *(const float4*)(qp + kq + 4);
        qf[2] = *(const float4*)(qp + 32 + kq);
        qf[3] = *(const float4*)(qp + 32 + kq + 4);
    }

    // ---- stage Kc (bf16) and VcT (bf16, transposed) ONCE per workgroup ----
    {
        const int j = tid >> 1;                // column 0..127
        const int h = (tid & 1) << 5;          // dim half: 0 or 32
        const size_t src = ((size_t)b * TSEQ + (j * 64 + 63)) * EDIM + h;
        const float4* ks = (const float4*)(K + src);
        const float4* vs = (const float4*)(V + src);
        #pragma unroll
        for (int t = 0; t < 8; ++t) {
            float4 kf = ks[t];
            unsigned int p0 = (unsigned int)f2bf(kf.x) | ((unsigned int)f2bf(kf.y) << 16);
            unsigned int p1 = (unsigned int)f2bf(kf.z) | ((unsigned int)f2bf(kf.w) << 16);
            *(unsigned int*)&Kc[j][h + 4 * t]     = p0;
            *(unsigned int*)&Kc[j][h + 4 * t + 2] = p1;
        }
        #pragma unroll
        for (int t = 0; t < 8; ++t) {
            float4 vf = vs[t];
            VcT[h + 4 * t + 0][j] = f2bf(vf.x);
            VcT[h + 4 * t + 1][j] = f2bf(vf.y);
            VcT[h + 4 * t + 2][j] = f2bf(vf.z);
            VcT[h + 4 * t + 3][j] = f2bf(vf.w);
        }
    }
    __syncthreads();                           // the ONLY barrier

    #pragma unroll
    for (int it = 0; it < MPG; ++it) {
        const int m = mg * MPG + it;
        const size_t rowbase = (size_t)b * TSEQ + ((size_t)m << 6);

        // ---- convert prefetched Q (pre-scaled by 0.125*log2e) ----
        short8 qa[2];
        #pragma unroll
        for (int s = 0; s < 2; ++s) {
            float4 f0 = qf[2 * s], f1 = qf[2 * s + 1];
            short8 v;
            v[0] = (short)f2bf(f0.x * QSCALE); v[1] = (short)f2bf(f0.y * QSCALE);
            v[2] = (short)f2bf(f0.z * QSCALE); v[3] = (short)f2bf(f0.w * QSCALE);
            v[4] = (short)f2bf(f1.x * QSCALE); v[5] = (short)f2bf(f1.y * QSCALE);
            v[6] = (short)f2bf(f1.z * QSCALE); v[7] = (short)f2bf(f1.w * QSCALE);
            qa[s] = v;
        }

        // ---- GEMM1: 8 col-tiles x 2 K-steps ----
        f32x4 acc[8];
        #pragma unroll
        for (int t = 0; t < 8; ++t) acc[t] = (f32x4)0.f;
        #pragma unroll
        for (int t = 0; t < 8; ++t) {
            const unsigned short* kr = &Kc[(t << 4) + c][0];
            short8 b0 = *(const short8*)(kr + kq);
            short8 b1 = *(const short8*)(kr + 32 + kq);
            acc[t] = __builtin_amdgcn_mfma_f32_16x16x32_bf16(qa[0], b0, acc[t], 0, 0, 0);
            acc[t] = __builtin_amdgcn_mfma_f32_16x16x32_bf16(qa[1], b1, acc[t], 0, 0, 0);
        }

        // ---- prefetch Q for next iteration ----
        if (it + 1 < MPG) {
            const float* qp = Q + (rowbase + 64 + qr) * EDIM;
            qf[0] = *(const float4*)(qp + kq);
            qf[1] = *(const float4*)(qp + kq + 4);
            qf[2] = *(const float4*)(qp + 32 + kq);
            qf[3] = *(const float4*)(qp + 32 + kq + 4);
        }

        // ---- mask + exp2 + row sums; normalize in registers ----
        #pragma unroll
        for (int reg = 0; reg < 4; ++reg) {
            const int r  = rb + reg;
            const int nv = m + (r == 63 ? 1 : 0);
            float sum = 0.f;
            #pragma unroll
            for (int t = 0; t < 8; ++t) {
                const int jc = (t << 4) + c;
                float e = (jc < nv) ? exp2f(acc[t][reg]) : 0.f;
                acc[t][reg] = e;
                sum += e;
            }
            sum += __shfl_xor(sum, 1); sum += __shfl_xor(sum, 2);
            sum += __shfl_xor(sum, 4); sum += __shfl_xor(sum, 8);
            const float rinv = (sum > 0.f) ? 1.0f / sum : 0.f;
            #pragma unroll
            for (int t = 0; t < 8; ++t) acc[t][reg] *= rinv;
        }

        // ---- Aw (bf16) -> LDS first (wave-private rows, no barrier);
        //      the lgkm drain overlaps the A store burst below ----
        #pragma unroll
        for (int reg = 0; reg < 4; ++reg) {
            #pragma unroll
            for (int t = 0; t < 8; ++t)
                Aw[rb + reg][(t << 4) + c] = f2bf(acc[t][reg]);
        }

        // ---- A output: directly from f32 accumulators (C-layout) ----
        #pragma unroll
        for (int reg = 0; reg < 4; ++reg) {
            float* ap = A + (rowbase + rb + reg) * NCOL + c;
            #pragma unroll
            for (int t = 0; t < 8; ++t) ap[t << 4] = acc[t][reg];
        }

        // ---- GEMM2: out(64x64) = Aw(64x128) . Vc(128x64) ----
        short8 af[4];
        {
            const unsigned short* ar = &Aw[qr][0];
            #pragma unroll
            for (int s = 0; s < 4; ++s) af[s] = *(const short8*)(ar + (s << 5) + kq);
        }
        f32x4 oacc[4];
        #pragma unroll
        for (int t = 0; t < 4; ++t) oacc[t] = (f32x4)0.f;
        #pragma unroll
        for (int t = 0; t < 4; ++t) {
            const unsigned short* vr = &VcT[(t << 4) + c][0];
            #pragma unroll
            for (int s = 0; s < 4; ++s) {
                short8 vb = *(const short8*)(vr + (s << 5) + kq);
                oacc[t] = __builtin_amdgcn_mfma_f32_16x16x32_bf16(af[s], vb, oacc[t], 0, 0, 0);
            }
        }

        // ---- Out: directly from C-layout regs ----
        #pragma unroll
        for (int t = 0; t < 4; ++t) {
            #pragma unroll
            for (int reg = 0; reg < 4; ++reg)
                Out[(rowbase + rb + reg) * EDIM + (t << 4) + c] = oacc[t][reg];
        }
    }
}

extern "C" void kernel_launch(void* const* d_in, const int* in_sizes, int n_in,
                              void* d_out, int out_size, void* d_ws, size_t ws_size,
                              hipStream_t stream) {
    const float* Q = (const float*)d_in[0];
    const float* K = (const float*)d_in[1];
    const float* V = (const float*)d_in[2];
    float* Out = (float*)d_out;
    float* A   = Out + (size_t)NBATCH * TSEQ * EDIM;

    // 512 workgroups x 256 threads: one per (batch, 4 m-blocks); 2 wgs/CU exact.
    cba_kernel<<<dim3(NBATCH * 32), dim3(256), 0, stream>>>(Q, K, V, Out, A);
}

// Round 9
// 173.069 us; speedup vs baseline: 1.0566x; 1.0079x over previous
//
#include <hip/hip_runtime.h>
#include <math.h>

// ColumnBlockAttention via bf16 MFMA: b=16, t=8192, e=64, BLOCK=64, n_cols=128
// d_out = [out: b*t*64 f32 | A: b*t*128 f32].
//
// One workgroup per (batch, 4 m-blocks); grid 512, 2 wgs/CU. Kc/VcT staged
// once. Per m-block iteration (loop NOT unrolled, one barrier):
//   GEMM1 Z=Q.Kc^T (bf16 mfma) -> mask/exp2 (unnormalized e)
//   -> Aw(bf16)->LDS (wave-private rows) -> barrier
//   -> GEMM2 over 5 n-tiles: tiles 0-3 = e.Vc, tile 4 = e.ones = ROW SUMS
//      (ones-column trick: VcT dim-row 64 == 1, rows 65-79 == 0)
//   -> rinv via ONE broadcast shuffle per reg -> all stores at iteration end:
//      A = e*rinv (direct from accs), Out = oacc*rinv.
// This removes the 16-serial-shuffle reduction from the critical chain.
// Layouts (HW-verified m89/m120): A-frag A[m=lane&15][k=(lane>>4)*8+j],
// B-frag B[k][n]: n=lane&15, k=(lane>>4)*8+j; C/D col=lane&15,
// row=(lane>>4)*4+reg.

#define TSEQ 8192
#define EDIM 64
#define NCOL 128
#define NBATCH 16
#define MPG 4            // m-blocks per workgroup

typedef __attribute__((ext_vector_type(8))) short short8;
typedef __attribute__((ext_vector_type(4))) float f32x4;

__device__ __forceinline__ unsigned short f2bf(float f) {   // RTNE bf16
    unsigned int u = __float_as_uint(f);
    return (unsigned short)((u + 0x7fffu + ((u >> 16) & 1u)) >> 16);
}

__global__ __launch_bounds__(256, 2)
void cba_kernel(const float* __restrict__ Q,
                const float* __restrict__ K,
                const float* __restrict__ V,
                float* __restrict__ Out,
                float* __restrict__ A)
{
    __shared__ unsigned short Kc[NCOL][72];    // Kc[col][dim]    (18432 B)
    __shared__ unsigned short VcT[80][136];    // VcT[dim][col]   (21760 B); dim64=1s
    __shared__ unsigned short Aw[64][136];     // e (bf16) [row][col] (17408 B)

    const int tid  = threadIdx.x;
    const int lane = tid & 63;
    const int wid  = tid >> 6;                 // 0..3: rows [16w,16w+16)
    const int b    = blockIdx.x >> 5;          // 0..15
    const int mg   = blockIdx.x & 31;          // m-group: m = 4*mg + it

    const int c   = lane & 15;                 // col-in-tile / n index
    const int kq  = (lane >> 4) << 3;          // 8-dim k-group base
    const int rb  = (wid << 4) + ((lane >> 4) << 2);  // C-layout row base (in 64)
    const int qr  = (wid << 4) + c;            // A-frag row (in 64)

    // 0.125 * log2(e): softmax(x/8) == exp2(QSCALE * x) / sum
    const float QSCALE = 0.18033688011112042f;

    // ---- prefetch Q for iteration 0 (issues before staging loads) ----
    float4 qf[4];
    {
        const float* qp = Q + ((size_t)b * TSEQ + ((mg * MPG) << 6) + qr) * EDIM;
        qf[0] = *(const float4*)(qp + kq);
        qf[1] = *(const float4*)(qp + kq + 4);
        qf[2] = *(const float4*)(qp + 32 + kq);
        qf[3] = *(const float4*)(qp + 32 + kq + 4);
    }

    // ---- stage Kc (bf16), VcT (bf16 transposed), ones/zero rows 64..79 ----
    {
        const int j = tid >> 1;                // column 0..127
        const int h = (tid & 1) << 5;          // dim half: 0 or 32
        const size_t src = ((size_t)b * TSEQ + (j * 64 + 63)) * EDIM + h;
        const float4* ks = (const float4*)(K + src);
        const float4* vs = (const float4*)(V + src);
        #pragma unroll
        for (int t = 0; t < 8; ++t) {
            float4 kf = ks[t];
            unsigned int p0 = (unsigned int)f2bf(kf.x) | ((unsigned int)f2bf(kf.y) << 16);
            unsigned int p1 = (unsigned int)f2bf(kf.z) | ((unsigned int)f2bf(kf.w) << 16);
            *(unsigned int*)&Kc[j][h + 4 * t]     = p0;
            *(unsigned int*)&Kc[j][h + 4 * t + 2] = p1;
        }
        #pragma unroll
        for (int t = 0; t < 8; ++t) {
            float4 vf = vs[t];
            VcT[h + 4 * t + 0][j] = f2bf(vf.x);
            VcT[h + 4 * t + 1][j] = f2bf(vf.y);
            VcT[h + 4 * t + 2][j] = f2bf(vf.z);
            VcT[h + 4 * t + 3][j] = f2bf(vf.w);
        }
        // rows 64..79: row 64 = 1.0 (bf16 0x3f80), rows 65..79 = 0
        const int r0 = 64 + ((tid & 1) << 3);  // 64 or 72
        #pragma unroll
        for (int t = 0; t < 8; ++t)
            VcT[r0 + t][j] = (r0 + t == 64) ? (unsigned short)0x3f80 : (unsigned short)0;
    }
    __syncthreads();                           // staging visible

    #pragma clang loop unroll(disable)
    for (int it = 0; it < MPG; ++it) {
        const int m = mg * MPG + it;
        const size_t rowbase = (size_t)b * TSEQ + ((size_t)m << 6);

        // ---- convert prefetched Q (pre-scaled by 0.125*log2e) ----
        short8 qa[2];
        #pragma unroll
        for (int s = 0; s < 2; ++s) {
            float4 f0 = qf[2 * s], f1 = qf[2 * s + 1];
            short8 v;
            v[0] = (short)f2bf(f0.x * QSCALE); v[1] = (short)f2bf(f0.y * QSCALE);
            v[2] = (short)f2bf(f0.z * QSCALE); v[3] = (short)f2bf(f0.w * QSCALE);
            v[4] = (short)f2bf(f1.x * QSCALE); v[5] = (short)f2bf(f1.y * QSCALE);
            v[6] = (short)f2bf(f1.z * QSCALE); v[7] = (short)f2bf(f1.w * QSCALE);
            qa[s] = v;
        }

        // ---- GEMM1: 8 col-tiles x 2 K-steps ----
        f32x4 acc[8];
        #pragma unroll
        for (int t = 0; t < 8; ++t) acc[t] = (f32x4)0.f;
        #pragma unroll
        for (int t = 0; t < 8; ++t) {
            const unsigned short* kr = &Kc[(t << 4) + c][0];
            short8 b0 = *(const short8*)(kr + kq);
            short8 b1 = *(const short8*)(kr + 32 + kq);
            acc[t] = __builtin_amdgcn_mfma_f32_16x16x32_bf16(qa[0], b0, acc[t], 0, 0, 0);
            acc[t] = __builtin_amdgcn_mfma_f32_16x16x32_bf16(qa[1], b1, acc[t], 0, 0, 0);
        }

        // ---- prefetch Q for next iteration ----
        if (it + 1 < MPG) {
            const float* qp = Q + (rowbase + 64 + qr) * EDIM;
            qf[0] = *(const float4*)(qp + kq);
            qf[1] = *(const float4*)(qp + kq + 4);
            qf[2] = *(const float4*)(qp + 32 + kq);
            qf[3] = *(const float4*)(qp + 32 + kq + 4);
        }

        // ---- mask + exp2 (UNNORMALIZED e stays in acc) ----
        #pragma unroll
        for (int reg = 0; reg < 4; ++reg) {
            const int nv = m + ((rb + reg) == 63 ? 1 : 0);
            #pragma unroll
            for (int t = 0; t < 8; ++t) {
                const int jc = (t << 4) + c;
                acc[t][reg] = (jc < nv) ? exp2f(acc[t][reg]) : 0.f;
            }
        }

        // ---- Aw (bf16, unnormalized) -> LDS (wave-private rows) ----
        #pragma unroll
        for (int reg = 0; reg < 4; ++reg) {
            #pragma unroll
            for (int t = 0; t < 8; ++t)
                Aw[rb + reg][(t << 4) + c] = f2bf(acc[t][reg]);
        }
        __syncthreads();                       // pacing fence (R6 winner had it)

        // ---- GEMM2 over 5 n-tiles: 0-3 = e.Vc, 4 = row sums (ones col) ----
        short8 af[4];
        {
            const unsigned short* ar = &Aw[qr][0];
            #pragma unroll
            for (int s = 0; s < 4; ++s) af[s] = *(const short8*)(ar + (s << 5) + kq);
        }
        f32x4 oacc[5];
        #pragma unroll
        for (int t = 0; t < 5; ++t) oacc[t] = (f32x4)0.f;
        #pragma unroll
        for (int t = 0; t < 5; ++t) {
            const unsigned short* vr = &VcT[(t << 4) + c][0];
            #pragma unroll
            for (int s = 0; s < 4; ++s) {
                short8 vb = *(const short8*)(vr + (s << 5) + kq);
                oacc[t] = __builtin_amdgcn_mfma_f32_16x16x32_bf16(af[s], vb, oacc[t], 0, 0, 0);
            }
        }

        // ---- rinv: row sums live in n-col 0 of tile 4 (lanes c==0);
        //      one broadcast shuffle per reg ----
        float rinv[4];
        #pragma unroll
        for (int reg = 0; reg < 4; ++reg) {
            float sum = __shfl(oacc[4][reg], lane & 48);
            rinv[reg] = (sum > 0.f) ? 1.0f / sum : 0.f;
        }

        // ---- stores at iteration end: A = e*rinv, Out = oacc*rinv ----
        #pragma unroll
        for (int reg = 0; reg < 4; ++reg) {
            float* ap = A + (rowbase + rb + reg) * NCOL + c;
            #pragma unroll
            for (int t = 0; t < 8; ++t) ap[t << 4] = acc[t][reg] * rinv[reg];
        }
        #pragma unroll
        for (int t = 0; t < 4; ++t) {
            #pragma unroll
            for (int reg = 0; reg < 4; ++reg)
                Out[(rowbase + rb + reg) * EDIM + (t << 4) + c] = oacc[t][reg] * rinv[reg];
        }
    }
}

extern "C" void kernel_launch(void* const* d_in, const int* in_sizes, int n_in,
                              void* d_out, int out_size, void* d_ws, size_t ws_size,
                              hipStream_t stream) {
    const float* Q = (const float*)d_in[0];
    const float* K = (const float*)d_in[1];
    const float* V = (const float*)d_in[2];
    float* Out = (float*)d_out;
    float* A   = Out + (size_t)NBATCH * TSEQ * EDIM;

    // 512 workgroups x 256 threads: one per (batch, 4 m-blocks); 2 wgs/CU exact.
    cba_kernel<<<dim3(NBATCH * 32), dim3(256), 0, stream>>>(Q, K, V, Out, A);
}